// Round 3
// baseline (3107.037 us; speedup 1.0000x reference)
//
#include <hip/hip_runtime.h>

// RNN: S=512, B=128, I=256, H=512, O=128
// R3: weight-resident recurrence with pinned VGPR fragments + port balancing.
//  Per wave (128 B-frags of W_hh, 1 KB each):
//    kt 0..9   -> 80 frags pinned in VGPRs (asm value-pin, 320 regs)
//    kt 10..12 -> 24 frags in LDS (96 KB/CU)
//    kt 13..15 -> 24 frags streamed from L2 each step (96 KB/CU/step)
//  VMEM port/step: 96(stream)+16(xh)+32(hs) = 144 KB @64 B/cyc ~ 2300 cyc
//  LDS  port/step: 64KB h-rd + 96KB W-rd + wr + hs-rd          ~ 2300 cyc
//  Swapped-operand MFMA (a=W, b=h): C layout [row=col16][col=quad*4+r]
//  -> epilogue h-writes are 8x ds_write_b64 per lane, not 32x u16.

typedef __attribute__((ext_vector_type(8))) short short8;   // 8 bf16
typedef __attribute__((ext_vector_type(4))) float f32x4;    // MFMA C/D
typedef __attribute__((ext_vector_type(2))) unsigned int uint2v;

__device__ __forceinline__ unsigned short f32_to_bf16(float f) {
  unsigned int u = __float_as_uint(f);
  u += 0x7FFFu + ((u >> 16) & 1u);
  return (unsigned short)(u >> 16);
}
__device__ __forceinline__ float fast_tanh(float x) {
  float e = __expf(2.0f * x);
  return 1.0f - 2.0f / (e + 1.0f);
}

// ---------------------------------------------------------------------------
// Pack K x N fp32 row-major -> bf16 MFMA fragment tiles.
// Tile (nt,kt): lane holds W[k=kt*32+(lane>>4)*8+j][n=nt*16+(lane&15)],
// stored P[tile*512 + lane*8 + j], tile = nt*(K/32)+kt.
// (Usable as B-frag, or as A-frag of W^T for swapped-operand MFMA.)
// ---------------------------------------------------------------------------
__global__ void pack_b_kernel(const float* __restrict__ W,
                              unsigned short* __restrict__ P, int K, int N) {
  int tid  = blockIdx.x * 256 + threadIdx.x;
  int lane = tid & 63;
  int tile = tid >> 6;
  int nKt  = K >> 5;
  int nTiles = (N >> 4) * nKt;
  if (tile >= nTiles) return;
  int nt = tile / nKt;
  int kt = tile - nt * nKt;
  int n  = (nt << 4) + (lane & 15);
  int k0 = (kt << 5) + ((lane >> 4) << 3);
  unsigned short* dst = P + (size_t)tile * 512 + lane * 8;
#pragma unroll
  for (int j = 0; j < 8; ++j)
    dst[j] = f32_to_bf16(W[(size_t)(k0 + j) * N + n]);
}

// ---------------------------------------------------------------------------
// Phase 1: xh = x@W_xh + b_h, swapped-operand MFMA; stored pre-swizzled:
// xh_s[((t*8+g)*4 + by)*2048 + lane*32 + nt*4 + r] =
//   xh[t][g*16 + (lane&15)][by*128 + nt*16 + (lane>>4)*4 + r]
// ---------------------------------------------------------------------------
__global__ __launch_bounds__(256) void xh_gemm_kernel(
    const float* __restrict__ x, const unsigned short* __restrict__ Wxh_p,
    const float* __restrict__ b_h, unsigned short* __restrict__ xh_s) {
  __shared__ __align__(16) unsigned short Abuf[64 * 264];
  const int tid = threadIdx.x;
  const int m0 = blockIdx.x * 64;
  const int by = blockIdx.y;                  // cols [by*128, by*128+128)

#pragma unroll
  for (int i = 0; i < 16; ++i) {
    int flat = i * 1024 + tid * 4;
    int row = flat >> 8, col = flat & 255;
    float4 v = *(const float4*)(x + (size_t)(m0 + row) * 256 + col);
    ushort4 u;
    u.x = f32_to_bf16(v.x); u.y = f32_to_bf16(v.y);
    u.z = f32_to_bf16(v.z); u.w = f32_to_bf16(v.w);
    *(ushort4*)(Abuf + row * 264 + col) = u;
  }
  __syncthreads();

  const int w2 = tid >> 6, lane = tid & 63;
  const int quad = lane >> 4, col16 = lane & 15;
  f32x4 acc[8];
#pragma unroll
  for (int nt = 0; nt < 8; ++nt) acc[nt] = (f32x4){0.f,0.f,0.f,0.f};
  const int aBase = (w2 * 16 + col16) * 264 + quad * 8;
#pragma unroll
  for (int kt = 0; kt < 8; ++kt) {
    short8 xfrag = *(const short8*)(Abuf + aBase + kt * 32);
#pragma unroll
    for (int nt = 0; nt < 8; ++nt) {
      int tile = (by * 8 + nt) * 8 + kt;      // nKt(Wxh)=8
      short8 wfrag = *(const short8*)(Wxh_p + (size_t)tile * 512 + lane * 8);
      // swapped: a=W frag, b=x frag -> acc[nt][r] = xh[row=col16][col=quad*4+r]
      acc[nt] = __builtin_amdgcn_mfma_f32_16x16x32_bf16(wfrag, xfrag, acc[nt], 0, 0, 0);
    }
  }
  const int t = (m0 + w2 * 16) >> 7;
  const int g = ((m0 + w2 * 16) & 127) >> 4;
  unsigned short hv[32];
#pragma unroll
  for (int nt = 0; nt < 8; ++nt) {
    float4 bh4 = *(const float4*)(b_h + by * 128 + nt * 16 + quad * 4);
#pragma unroll
    for (int r = 0; r < 4; ++r)
      hv[nt * 4 + r] = f32_to_bf16(acc[nt][r] + (&bh4.x)[r]);
  }
  unsigned short* dst = xh_s + ((size_t)(t * 8 + g) * 4 + by) * 2048 + lane * 32;
#pragma unroll
  for (int k = 0; k < 4; ++k) {
    uint4 u;
    u.x = (unsigned)hv[k*8+0] | ((unsigned)hv[k*8+1] << 16);
    u.y = (unsigned)hv[k*8+2] | ((unsigned)hv[k*8+3] << 16);
    u.z = (unsigned)hv[k*8+4] | ((unsigned)hv[k*8+5] << 16);
    u.w = (unsigned)hv[k*8+6] | ((unsigned)hv[k*8+7] << 16);
    *(uint4*)(dst + k * 8) = u;
  }
}

// ---------------------------------------------------------------------------
// Phase 2: recurrence. grid 8, block 256 (1 wave/SIMD).
// ---------------------------------------------------------------------------
__global__ __launch_bounds__(256, 1) void rnn_recurrence_kernel(
    const unsigned short* __restrict__ Whh_p,
    unsigned short* __restrict__ xhs) {          // xh_s in, hs out (in-place)
  __shared__ __align__(16) unsigned short Hb[2][16 * 520];   // 33,280 B
  __shared__ __align__(16) unsigned short Wl[4][24 * 512];   // 98,304 B
  const int tid = threadIdx.x;
  const int w = tid >> 6, lane = tid & 63;
  const int quad = lane >> 4, col16 = lane & 15;
  const int g = blockIdx.x;

  for (int i = tid; i < 2 * 16 * 520; i += 256) (&Hb[0][0])[i] = 0;

  // kt 0..9: VGPR-resident, value-pinned so they cannot be rematerialized.
  short8 wf[80];
#pragma unroll
  for (int f = 0; f < 80; ++f) {
    int kt = f >> 3, nt = f & 7;
    wf[f] = *(const short8*)(
        Whh_p + ((size_t)((w * 8 + nt) * 16 + kt)) * 512 + lane * 8);
  }
#pragma unroll
  for (int f = 0; f < 80; ++f) asm volatile("" : "+v"(wf[f]));

  // kt 10..12: LDS-resident.
  unsigned short* wlw = Wl[w];
#pragma unroll
  for (int idx = 0; idx < 24; ++idx) {
    int kt = 10 + (idx >> 3), nt = idx & 7;
    short8 v = *(const short8*)(
        Whh_p + ((size_t)((w * 8 + nt) * 16 + kt)) * 512 + lane * 8);
    *(short8*)(wlw + idx * 512 + lane * 8) = v;
  }
  __syncthreads();

  const unsigned short* wlwL = wlw + lane * 8;
  const int aOff = col16 * 520 + quad * 8;        // h-frag base (row=col16)
  const int hrow = tid >> 4, hcol = (tid & 15) * 32;
  const int rbOff = hrow * 520 + hcol;
  unsigned short* hsW = xhs + (size_t)g * 8192 + hrow * 512 + hcol;
  const unsigned short* xhL = xhs + (size_t)g * 8192 + (size_t)w * 2048 + lane * 32;
  const unsigned short* wstream = Whh_p + lane * 8;
  const int wbW = col16 * 520 + w * 128;          // epilogue write base

#pragma unroll 1
  for (int t = 0; t < 512; ++t) {
    const unsigned short* rb = Hb[t & 1];
    unsigned short* wb = Hb[(t & 1) ^ 1];

    // Launder streamed base per-iteration so loads stay inside the loop.
    unsigned long long up = (unsigned long long)wstream;
    asm volatile("" : "+v"(up));
    const unsigned short* pS = (const unsigned short*)up;

    // Streamed group kt13 (consumed at kt13).
    short8 s13[8];
#pragma unroll
    for (int nt = 0; nt < 8; ++nt)
      s13[nt] = *(const short8*)(pS + ((size_t)((w * 8 + nt) * 16 + 13)) * 512);

    // hs store of h_{t-1} (window == consumed xh[t-1] window).
    if (t > 0) {
#pragma unroll
      for (int k = 0; k < 4; ++k) {
        short8 v = *(const short8*)(rb + rbOff + k * 8);
        *(short8*)(hsW + (size_t)(t - 1) * 65536 + k * 8) = v;
      }
    }

    // xh for this step (4 coalesced dwordx4).
    uint4 xq0 = *(const uint4*)(xhL + (size_t)t * 65536);
    uint4 xq1 = *(const uint4*)(xhL + (size_t)t * 65536 + 8);
    uint4 xq2 = *(const uint4*)(xhL + (size_t)t * 65536 + 16);
    uint4 xq3 = *(const uint4*)(xhL + (size_t)t * 65536 + 24);

    f32x4 acc[8];
#pragma unroll
    for (int nt = 0; nt < 8; ++nt) acc[nt] = (f32x4){0.f,0.f,0.f,0.f};

    // kt 0..8 from VGPRs.
#pragma unroll
    for (int kt = 0; kt < 9; ++kt) {
      short8 h = *(const short8*)(rb + aOff + kt * 32);
#pragma unroll
      for (int nt = 0; nt < 8; ++nt)
        acc[nt] = __builtin_amdgcn_mfma_f32_16x16x32_bf16(wf[kt * 8 + nt], h, acc[nt], 0, 0, 0);
    }
    // Streamed group kt14.
    short8 s14[8];
#pragma unroll
    for (int nt = 0; nt < 8; ++nt)
      s14[nt] = *(const short8*)(pS + ((size_t)((w * 8 + nt) * 16 + 14)) * 512);
    // kt 9 from VGPRs.
    {
      short8 h = *(const short8*)(rb + aOff + 9 * 32);
#pragma unroll
      for (int nt = 0; nt < 8; ++nt)
        acc[nt] = __builtin_amdgcn_mfma_f32_16x16x32_bf16(wf[72 + nt], h, acc[nt], 0, 0, 0);
    }
    // kt 10..11 from LDS.
#pragma unroll
    for (int kt = 10; kt < 12; ++kt) {
      short8 h = *(const short8*)(rb + aOff + kt * 32);
#pragma unroll
      for (int nt = 0; nt < 8; ++nt) {
        short8 b = *(const short8*)(wlwL + ((kt - 10) * 8 + nt) * 512);
        acc[nt] = __builtin_amdgcn_mfma_f32_16x16x32_bf16(b, h, acc[nt], 0, 0, 0);
      }
    }
    // Streamed group kt15.
    short8 s15[8];
#pragma unroll
    for (int nt = 0; nt < 8; ++nt)
      s15[nt] = *(const short8*)(pS + ((size_t)((w * 8 + nt) * 16 + 15)) * 512);
    // kt 12 from LDS.
    {
      short8 h = *(const short8*)(rb + aOff + 12 * 32);
#pragma unroll
      for (int nt = 0; nt < 8; ++nt) {
        short8 b = *(const short8*)(wlwL + (16 + nt) * 512);
        acc[nt] = __builtin_amdgcn_mfma_f32_16x16x32_bf16(b, h, acc[nt], 0, 0, 0);
      }
    }
    // kt 13..15 streamed.
    {
      short8 h = *(const short8*)(rb + aOff + 13 * 32);
#pragma unroll
      for (int nt = 0; nt < 8; ++nt)
        acc[nt] = __builtin_amdgcn_mfma_f32_16x16x32_bf16(s13[nt], h, acc[nt], 0, 0, 0);
    }
    {
      short8 h = *(const short8*)(rb + aOff + 14 * 32);
#pragma unroll
      for (int nt = 0; nt < 8; ++nt)
        acc[nt] = __builtin_amdgcn_mfma_f32_16x16x32_bf16(s14[nt], h, acc[nt], 0, 0, 0);
    }
    {
      short8 h = *(const short8*)(rb + aOff + 15 * 32);
#pragma unroll
      for (int nt = 0; nt < 8; ++nt)
        acc[nt] = __builtin_amdgcn_mfma_f32_16x16x32_bf16(s15[nt], h, acc[nt], 0, 0, 0);
    }

    // Epilogue: h_t = tanh(xh + acc); acc[nt][r] = h_pre[row=col16][col=w*128+nt*16+quad*4+r]
    unsigned xw[16] = {xq0.x, xq0.y, xq0.z, xq0.w, xq1.x, xq1.y, xq1.z, xq1.w,
                       xq2.x, xq2.y, xq2.z, xq2.w, xq3.x, xq3.y, xq3.z, xq3.w};
#pragma unroll
    for (int nt = 0; nt < 8; ++nt) {
      float hv[4];
#pragma unroll
      for (int r = 0; r < 4; ++r) {
        int j = nt * 4 + r;
        unsigned uu = xw[j >> 1];
        float xv = (j & 1) ? __uint_as_float(uu & 0xFFFF0000u)
                           : __uint_as_float(uu << 16);
        hv[r] = fast_tanh(acc[nt][r] + xv);
      }
      uint2v o;
      o.x = (unsigned)f32_to_bf16(hv[0]) | ((unsigned)f32_to_bf16(hv[1]) << 16);
      o.y = (unsigned)f32_to_bf16(hv[2]) | ((unsigned)f32_to_bf16(hv[3]) << 16);
      *(uint2v*)(wb + wbW + nt * 16 + quad * 4) = o;
    }
    __syncthreads();
  }

  // Final hs store: h_511 lives in Hb[0].
  {
    const unsigned short* rb = Hb[0];
#pragma unroll
    for (int k = 0; k < 4; ++k) {
      short8 v = *(const short8*)(rb + rbOff + k * 8);
      *(short8*)(hsW + (size_t)511 * 65536 + k * 8) = v;
    }
  }
}

// ---------------------------------------------------------------------------
// Phase 3: out = hs @ W_hy + b_y.  [65536,512]@[512,128] fp32 out.
// ---------------------------------------------------------------------------
__global__ __launch_bounds__(256) void out_gemm_kernel(
    const unsigned short* __restrict__ hs, const unsigned short* __restrict__ Why_p,
    const float* __restrict__ b_y, float* __restrict__ out) {
  const int tid = threadIdx.x;
  const int w = tid >> 6, lane = tid & 63;
  const int quad = lane >> 4, col16 = lane & 15;
  const int m0 = blockIdx.x * 64 + w * 16;

  f32x4 acc[8];
#pragma unroll
  for (int nt = 0; nt < 8; ++nt) acc[nt] = (f32x4){0.f,0.f,0.f,0.f};

  const unsigned short* aP = hs + (size_t)(m0 + col16) * 512 + quad * 8;
#pragma unroll
  for (int kt = 0; kt < 16; ++kt) {
    short8 a = *(const short8*)(aP + kt * 32);
#pragma unroll
    for (int nt = 0; nt < 8; ++nt) {
      int tile = nt * 16 + kt;                 // nKt(Why)=16
      short8 b = *(const short8*)(Why_p + (size_t)tile * 512 + lane * 8);
      acc[nt] = __builtin_amdgcn_mfma_f32_16x16x32_bf16(a, b, acc[nt], 0, 0, 0);
    }
  }
#pragma unroll
  for (int nt = 0; nt < 8; ++nt) {
    int n = nt * 16 + col16;
    float by = b_y[n];
#pragma unroll
    for (int r = 0; r < 4; ++r)
      out[(size_t)(m0 + quad * 4 + r) * 128 + n] = acc[nt][r] + by;
  }
}

// ---------------------------------------------------------------------------
extern "C" void kernel_launch(void* const* d_in, const int* in_sizes, int n_in,
                              void* d_out, int out_size, void* d_ws, size_t ws_size,
                              hipStream_t stream) {
  const float* x    = (const float*)d_in[0];   // [512,128,256]
  const float* W_xh = (const float*)d_in[1];   // [256,512]
  const float* W_hh = (const float*)d_in[2];   // [512,512]
  const float* W_hy = (const float*)d_in[3];   // [512,128]
  const float* b_h  = (const float*)d_in[4];   // [512]
  const float* b_y  = (const float*)d_in[5];   // [128]
  float* out = (float*)d_out;                  // [512,128,128]

  char* ws = (char*)d_ws;
  unsigned short* Wxh_p = (unsigned short*)(ws);                 // 256 KB
  unsigned short* Whh_p = (unsigned short*)(ws + (256 << 10));   // 512 KB
  unsigned short* Why_p = (unsigned short*)(ws + (768 << 10));   // 128 KB
  unsigned short* xhs   = (unsigned short*)(ws + (1024 << 10));  // 64 MB

  pack_b_kernel<<<64, 256, 0, stream>>>(W_xh, Wxh_p, 256, 512);
  pack_b_kernel<<<128, 256, 0, stream>>>(W_hh, Whh_p, 512, 512);
  pack_b_kernel<<<32, 256, 0, stream>>>(W_hy, Why_p, 512, 128);

  dim3 g1(1024, 4);
  xh_gemm_kernel<<<g1, 256, 0, stream>>>(x, Wxh_p, b_h, xhs);

  rnn_recurrence_kernel<<<8, 256, 0, stream>>>(Whh_p, xhs);

  out_gemm_kernel<<<1024, 256, 0, stream>>>(xhs, Why_p, b_y, out);
}

// Round 4
// 2321.171 us; speedup vs baseline: 1.3386x; 1.3386x over previous
//
#include <hip/hip_runtime.h>

// RNN: S=512, B=128, I=256, H=512, O=128
// R4: AGPR-resident weights. Arch VGPRs cap at 256 (8-bit encoding) -- R2/R3
// residency plans >256 arch regs were unallocatable (remat / scratch spill).
// gfx950 MFMA reads A/B straight from AGPRs, so per wave (128 W_hh frags):
//   kt 0..7              -> 64 frags pinned in AGPRs (exactly 256 AGPRs)
//   kt 8..10, kt11 nt0..6 -> 31 frags in LDS (124 KB/CU)
//   kt11 nt7, kt12..15   -> 33 frags streamed from L2 each step (132 KB)
// h double-buffered in LDS (33 KB); 1 barrier/step; hs written over
// consumed xh windows (in-place).

typedef __attribute__((ext_vector_type(8))) short short8;   // 8 bf16
typedef __attribute__((ext_vector_type(4))) float f32x4;    // MFMA C/D
typedef __attribute__((ext_vector_type(2))) unsigned int uint2v;

__device__ __forceinline__ unsigned short f32_to_bf16(float f) {
  unsigned int u = __float_as_uint(f);
  u += 0x7FFFu + ((u >> 16) & 1u);
  return (unsigned short)(u >> 16);
}
__device__ __forceinline__ float fast_tanh(float x) {
  float e = __expf(2.0f * x);
  return 1.0f - 2.0f / (e + 1.0f);
}

// ---------------------------------------------------------------------------
// Pack K x N fp32 row-major -> bf16 MFMA fragment tiles.
// Tile (nt,kt): lane holds W[k=kt*32+(lane>>4)*8+j][n=nt*16+(lane&15)],
// stored P[tile*512 + lane*8 + j], tile = nt*(K/32)+kt.
// ---------------------------------------------------------------------------
__global__ void pack_b_kernel(const float* __restrict__ W,
                              unsigned short* __restrict__ P, int K, int N) {
  int tid  = blockIdx.x * 256 + threadIdx.x;
  int lane = tid & 63;
  int tile = tid >> 6;
  int nKt  = K >> 5;
  int nTiles = (N >> 4) * nKt;
  if (tile >= nTiles) return;
  int nt = tile / nKt;
  int kt = tile - nt * nKt;
  int n  = (nt << 4) + (lane & 15);
  int k0 = (kt << 5) + ((lane >> 4) << 3);
  unsigned short* dst = P + (size_t)tile * 512 + lane * 8;
#pragma unroll
  for (int j = 0; j < 8; ++j)
    dst[j] = f32_to_bf16(W[(size_t)(k0 + j) * N + n]);
}

// ---------------------------------------------------------------------------
// Phase 1: xh = x@W_xh + b_h, swapped-operand MFMA; stored pre-swizzled:
// xh_s[((t*8+g)*4 + by)*2048 + lane*32 + nt*4 + r] =
//   xh[t][g*16 + (lane&15)][by*128 + nt*16 + (lane>>4)*4 + r]
// grid 1024; by-loop internal so x is read from HBM exactly once.
// ---------------------------------------------------------------------------
__global__ __launch_bounds__(256) void xh_gemm_kernel(
    const float* __restrict__ x, const unsigned short* __restrict__ Wxh_p,
    const float* __restrict__ b_h, unsigned short* __restrict__ xh_s) {
  __shared__ __align__(16) unsigned short Abuf[64 * 264];
  const int tid = threadIdx.x;
  const int m0 = blockIdx.x * 64;

#pragma unroll
  for (int i = 0; i < 16; ++i) {
    int flat = i * 1024 + tid * 4;
    int row = flat >> 8, col = flat & 255;
    float4 v = *(const float4*)(x + (size_t)(m0 + row) * 256 + col);
    ushort4 u;
    u.x = f32_to_bf16(v.x); u.y = f32_to_bf16(v.y);
    u.z = f32_to_bf16(v.z); u.w = f32_to_bf16(v.w);
    *(ushort4*)(Abuf + row * 264 + col) = u;
  }
  __syncthreads();

  const int w2 = tid >> 6, lane = tid & 63;
  const int quad = lane >> 4, col16 = lane & 15;
  const int aBase = (w2 * 16 + col16) * 264 + quad * 8;
  const int t = (m0 + w2 * 16) >> 7;
  const int g = ((m0 + w2 * 16) & 127) >> 4;

  for (int by = 0; by < 4; ++by) {
    f32x4 acc[8];
#pragma unroll
    for (int nt = 0; nt < 8; ++nt) acc[nt] = (f32x4){0.f,0.f,0.f,0.f};
#pragma unroll
    for (int kt = 0; kt < 8; ++kt) {
      short8 xfrag = *(const short8*)(Abuf + aBase + kt * 32);
#pragma unroll
      for (int nt = 0; nt < 8; ++nt) {
        int tile = (by * 8 + nt) * 8 + kt;      // nKt(Wxh)=8
        short8 wfrag = *(const short8*)(Wxh_p + (size_t)tile * 512 + lane * 8);
        acc[nt] = __builtin_amdgcn_mfma_f32_16x16x32_bf16(wfrag, xfrag, acc[nt], 0, 0, 0);
      }
    }
    unsigned short hv[32];
#pragma unroll
    for (int nt = 0; nt < 8; ++nt) {
      float4 bh4 = *(const float4*)(b_h + by * 128 + nt * 16 + quad * 4);
#pragma unroll
      for (int r = 0; r < 4; ++r)
        hv[nt * 4 + r] = f32_to_bf16(acc[nt][r] + (&bh4.x)[r]);
    }
    unsigned short* dst = xh_s + ((size_t)(t * 8 + g) * 4 + by) * 2048 + lane * 32;
#pragma unroll
    for (int k = 0; k < 4; ++k) {
      uint4 u;
      u.x = (unsigned)hv[k*8+0] | ((unsigned)hv[k*8+1] << 16);
      u.y = (unsigned)hv[k*8+2] | ((unsigned)hv[k*8+3] << 16);
      u.z = (unsigned)hv[k*8+4] | ((unsigned)hv[k*8+5] << 16);
      u.w = (unsigned)hv[k*8+6] | ((unsigned)hv[k*8+7] << 16);
      *(uint4*)(dst + k * 8) = u;
    }
  }
}

// ---------------------------------------------------------------------------
// Phase 2: recurrence. grid 8, block 256 (1 wave/SIMD).
// ---------------------------------------------------------------------------
__global__ __launch_bounds__(256, 1) void rnn_recurrence_kernel(
    const unsigned short* __restrict__ Whh_p,
    unsigned short* __restrict__ xhs) {          // xh_s in, hs out (in-place)
  __shared__ __align__(16) unsigned short Hb[2][16 * 520];   // 33,280 B
  __shared__ __align__(16) unsigned short Wl[4][31 * 512];   // 126,976 B
  const int tid = threadIdx.x;
  const int w = tid >> 6, lane = tid & 63;
  const int quad = lane >> 4, col16 = lane & 15;
  const int g = blockIdx.x;

  for (int i = tid; i < 2 * 16 * 520; i += 256) (&Hb[0][0])[i] = 0;

  // kt 0..7: 64 frags -> AGPRs (exactly 256). Empty asm with "+a" pins the
  // value into the AGPR class and makes it opaque (no remat, no demotion).
  short8 wf[64];
#pragma unroll
  for (int f = 0; f < 64; ++f) {
    int kt = f >> 3, nt = f & 7;
    wf[f] = *(const short8*)(
        Whh_p + ((size_t)((w * 8 + nt) * 16 + kt)) * 512 + lane * 8);
  }
#pragma unroll
  for (int f = 0; f < 64; ++f) asm volatile("" : "+a"(wf[f]));

  // kt 8..10 (all nt) + kt11 nt0..6: LDS-resident.
  unsigned short* wlw = Wl[w];
#pragma unroll
  for (int idx = 0; idx < 31; ++idx) {
    int kt = (idx < 24) ? (8 + (idx >> 3)) : 11;
    int nt = (idx < 24) ? (idx & 7) : (idx - 24);
    short8 v = *(const short8*)(
        Whh_p + ((size_t)((w * 8 + nt) * 16 + kt)) * 512 + lane * 8);
    *(short8*)(wlw + idx * 512 + lane * 8) = v;
  }
  __syncthreads();

  const unsigned short* wlwL = wlw + lane * 8;
  const int aOff = col16 * 520 + quad * 8;        // h-frag base (row=col16)
  const int hrow = tid >> 4, hcol = (tid & 15) * 32;
  const int rbOff = hrow * 520 + hcol;
  unsigned short* hsW = xhs + (size_t)g * 8192 + hrow * 512 + hcol;
  const unsigned short* xhL = xhs + (size_t)g * 8192 + (size_t)w * 2048 + lane * 32;
  const unsigned short* wstream = Whh_p + lane * 8;
  const int wbW = col16 * 520 + w * 128;          // epilogue write base

#pragma unroll 1
  for (int t = 0; t < 512; ++t) {
    const unsigned short* rb = Hb[t & 1];
    unsigned short* wb = Hb[(t & 1) ^ 1];

    // Launder streamed base per-iteration so loads stay inside the loop.
    unsigned long long up = (unsigned long long)wstream;
    asm volatile("" : "+v"(up));
    const unsigned short* pS = (const unsigned short*)up;

    // Stream group A: kt11 nt7 + kt12 (9 frags), consumed at kt11/12.
    short8 sA7 = *(const short8*)(pS + ((size_t)((w * 8 + 7) * 16 + 11)) * 512);
    short8 sA[8];
#pragma unroll
    for (int nt = 0; nt < 8; ++nt)
      sA[nt] = *(const short8*)(pS + ((size_t)((w * 8 + nt) * 16 + 12)) * 512);

    // hs store of h_{t-1} (window == consumed xh[t-1] window).
    if (t > 0) {
#pragma unroll
      for (int k = 0; k < 4; ++k) {
        short8 v = *(const short8*)(rb + rbOff + k * 8);
        *(short8*)(hsW + (size_t)(t - 1) * 65536 + k * 8) = v;
      }
    }

    // xh for this step (4 coalesced dwordx4).
    uint4 xq0 = *(const uint4*)(xhL + (size_t)t * 65536);
    uint4 xq1 = *(const uint4*)(xhL + (size_t)t * 65536 + 8);
    uint4 xq2 = *(const uint4*)(xhL + (size_t)t * 65536 + 16);
    uint4 xq3 = *(const uint4*)(xhL + (size_t)t * 65536 + 24);

    f32x4 acc[8];
#pragma unroll
    for (int nt = 0; nt < 8; ++nt) acc[nt] = (f32x4){0.f,0.f,0.f,0.f};

    // kt 0..7 from AGPRs.
#pragma unroll
    for (int kt = 0; kt < 8; ++kt) {
      short8 h = *(const short8*)(rb + aOff + kt * 32);
#pragma unroll
      for (int nt = 0; nt < 8; ++nt)
        acc[nt] = __builtin_amdgcn_mfma_f32_16x16x32_bf16(wf[kt * 8 + nt], h, acc[nt], 0, 0, 0);
    }

    // Stream group B: kt13..15 (24 frags), consumed at loop end.
    short8 sB13[8], sB14[8], sB15[8];
#pragma unroll
    for (int nt = 0; nt < 8; ++nt)
      sB13[nt] = *(const short8*)(pS + ((size_t)((w * 8 + nt) * 16 + 13)) * 512);
#pragma unroll
    for (int nt = 0; nt < 8; ++nt)
      sB14[nt] = *(const short8*)(pS + ((size_t)((w * 8 + nt) * 16 + 14)) * 512);
#pragma unroll
    for (int nt = 0; nt < 8; ++nt)
      sB15[nt] = *(const short8*)(pS + ((size_t)((w * 8 + nt) * 16 + 15)) * 512);

    // kt 8..10 from LDS.
#pragma unroll
    for (int kt = 8; kt < 11; ++kt) {
      short8 h = *(const short8*)(rb + aOff + kt * 32);
#pragma unroll
      for (int nt = 0; nt < 8; ++nt) {
        short8 b = *(const short8*)(wlwL + ((kt - 8) * 8 + nt) * 512);
        acc[nt] = __builtin_amdgcn_mfma_f32_16x16x32_bf16(b, h, acc[nt], 0, 0, 0);
      }
    }
    // kt 11: nt0..6 LDS, nt7 streamed.
    {
      short8 h = *(const short8*)(rb + aOff + 11 * 32);
#pragma unroll
      for (int nt = 0; nt < 7; ++nt) {
        short8 b = *(const short8*)(wlwL + (24 + nt) * 512);
        acc[nt] = __builtin_amdgcn_mfma_f32_16x16x32_bf16(b, h, acc[nt], 0, 0, 0);
      }
      acc[7] = __builtin_amdgcn_mfma_f32_16x16x32_bf16(sA7, h, acc[7], 0, 0, 0);
    }
    // kt 12..15 streamed.
    {
      short8 h = *(const short8*)(rb + aOff + 12 * 32);
#pragma unroll
      for (int nt = 0; nt < 8; ++nt)
        acc[nt] = __builtin_amdgcn_mfma_f32_16x16x32_bf16(sA[nt], h, acc[nt], 0, 0, 0);
    }
    {
      short8 h = *(const short8*)(rb + aOff + 13 * 32);
#pragma unroll
      for (int nt = 0; nt < 8; ++nt)
        acc[nt] = __builtin_amdgcn_mfma_f32_16x16x32_bf16(sB13[nt], h, acc[nt], 0, 0, 0);
    }
    {
      short8 h = *(const short8*)(rb + aOff + 14 * 32);
#pragma unroll
      for (int nt = 0; nt < 8; ++nt)
        acc[nt] = __builtin_amdgcn_mfma_f32_16x16x32_bf16(sB14[nt], h, acc[nt], 0, 0, 0);
    }
    {
      short8 h = *(const short8*)(rb + aOff + 15 * 32);
#pragma unroll
      for (int nt = 0; nt < 8; ++nt)
        acc[nt] = __builtin_amdgcn_mfma_f32_16x16x32_bf16(sB15[nt], h, acc[nt], 0, 0, 0);
    }

    // Epilogue: h_t = tanh(xh + acc); acc[nt][r] = h_pre[row=col16][col=w*128+nt*16+quad*4+r]
    unsigned xw[16] = {xq0.x, xq0.y, xq0.z, xq0.w, xq1.x, xq1.y, xq1.z, xq1.w,
                       xq2.x, xq2.y, xq2.z, xq2.w, xq3.x, xq3.y, xq3.z, xq3.w};
#pragma unroll
    for (int nt = 0; nt < 8; ++nt) {
      float hv[4];
#pragma unroll
      for (int r = 0; r < 4; ++r) {
        int j = nt * 4 + r;
        unsigned uu = xw[j >> 1];
        float xv = (j & 1) ? __uint_as_float(uu & 0xFFFF0000u)
                           : __uint_as_float(uu << 16);
        hv[r] = fast_tanh(acc[nt][r] + xv);
      }
      uint2v o;
      o.x = (unsigned)f32_to_bf16(hv[0]) | ((unsigned)f32_to_bf16(hv[1]) << 16);
      o.y = (unsigned)f32_to_bf16(hv[2]) | ((unsigned)f32_to_bf16(hv[3]) << 16);
      *(uint2v*)(wb + wbW + nt * 16 + quad * 4) = o;
    }
    __syncthreads();
  }

  // Final hs store: h_511 lives in Hb[0].
  {
    const unsigned short* rb = Hb[0];
#pragma unroll
    for (int k = 0; k < 4; ++k) {
      short8 v = *(const short8*)(rb + rbOff + k * 8);
      *(short8*)(hsW + (size_t)511 * 65536 + k * 8) = v;
    }
  }
}

// ---------------------------------------------------------------------------
// Phase 3: out = hs @ W_hy + b_y.  [65536,512]@[512,128] fp32 out.
// ---------------------------------------------------------------------------
__global__ __launch_bounds__(256) void out_gemm_kernel(
    const unsigned short* __restrict__ hs, const unsigned short* __restrict__ Why_p,
    const float* __restrict__ b_y, float* __restrict__ out) {
  const int tid = threadIdx.x;
  const int w = tid >> 6, lane = tid & 63;
  const int quad = lane >> 4, col16 = lane & 15;
  const int m0 = blockIdx.x * 64 + w * 16;

  f32x4 acc[8];
#pragma unroll
  for (int nt = 0; nt < 8; ++nt) acc[nt] = (f32x4){0.f,0.f,0.f,0.f};

  const unsigned short* aP = hs + (size_t)(m0 + col16) * 512 + quad * 8;
#pragma unroll
  for (int kt = 0; kt < 16; ++kt) {
    short8 a = *(const short8*)(aP + kt * 32);
#pragma unroll
    for (int nt = 0; nt < 8; ++nt) {
      int tile = nt * 16 + kt;                 // nKt(Why)=16
      short8 b = *(const short8*)(Why_p + (size_t)tile * 512 + lane * 8);
      acc[nt] = __builtin_amdgcn_mfma_f32_16x16x32_bf16(a, b, acc[nt], 0, 0, 0);
    }
  }
#pragma unroll
  for (int nt = 0; nt < 8; ++nt) {
    int n = nt * 16 + col16;
    float by = b_y[n];
#pragma unroll
    for (int r = 0; r < 4; ++r)
      out[(size_t)(m0 + quad * 4 + r) * 128 + n] = acc[nt][r] + by;
  }
}

// ---------------------------------------------------------------------------
extern "C" void kernel_launch(void* const* d_in, const int* in_sizes, int n_in,
                              void* d_out, int out_size, void* d_ws, size_t ws_size,
                              hipStream_t stream) {
  const float* x    = (const float*)d_in[0];   // [512,128,256]
  const float* W_xh = (const float*)d_in[1];   // [256,512]
  const float* W_hh = (const float*)d_in[2];   // [512,512]
  const float* W_hy = (const float*)d_in[3];   // [512,128]
  const float* b_h  = (const float*)d_in[4];   // [512]
  const float* b_y  = (const float*)d_in[5];   // [128]
  float* out = (float*)d_out;                  // [512,128,128]

  char* ws = (char*)d_ws;
  unsigned short* Wxh_p = (unsigned short*)(ws);                 // 256 KB
  unsigned short* Whh_p = (unsigned short*)(ws + (256 << 10));   // 512 KB
  unsigned short* Why_p = (unsigned short*)(ws + (768 << 10));   // 128 KB
  unsigned short* xhs   = (unsigned short*)(ws + (1024 << 10));  // 64 MB

  pack_b_kernel<<<64, 256, 0, stream>>>(W_xh, Wxh_p, 256, 512);
  pack_b_kernel<<<128, 256, 0, stream>>>(W_hh, Whh_p, 512, 512);
  pack_b_kernel<<<32, 256, 0, stream>>>(W_hy, Why_p, 512, 128);

  xh_gemm_kernel<<<1024, 256, 0, stream>>>(x, Wxh_p, b_h, xhs);

  rnn_recurrence_kernel<<<8, 256, 0, stream>>>(Whh_p, xhs);

  out_gemm_kernel<<<1024, 256, 0, stream>>>(xhs, Why_p, b_y, out);
}